// Round 1
// 706.618 us; speedup vs baseline: 1.0020x; 1.0020x over previous
//
#include <hip/hip_runtime.h>

// SpatialGraphConv: N=100000 nodes, CIN=COUT=32, T=12, E=1600000 edges.
// out[n,d,t] = b[d] + sum_c W[c,d] * agg[n,c,t],
// agg[n,:,:] = dinv[n]^2 * x[n,:,:] + sum_{e: dst=n} dinv[src]*w_e*dinv[n] * x[src,:,:]
// deg[n] = 1.0 (self loop) + sum_{e: dst=n} edge_attr[e];  dinv = rsqrt(deg)

constexpr int CIN  = 32;
constexpr int TT   = 12;
constexpr int COUT = 32;
constexpr int FPN  = CIN * TT;   // 384 floats per node row
constexpr int SROW = 388;        // padded LDS row

typedef float f4 __attribute__((ext_vector_type(4)));   // native vec for nontemporal

// Packed histogram: bits [44,64) = edge count, bits [0,44) = sum(ea) in 2^-20 fixed point.
// Max sum = 1.6M * 2^20 = 2^40.6 < 2^44; count max 2^20 >> max degree. Quantization
// error on deg <= deg_max * 2^-20 ~ 1e-4 absolute -> dinv rel error ~5e-5, negligible.
constexpr unsigned long long CNT_ONE = 1ULL << 44;
constexpr unsigned long long SUM_MASK = CNT_ONE - 1;

// ---------------- pass 1: packed histogram + per-edge rank ----------------

__global__ void k_hist(const int* __restrict__ ei, const float* __restrict__ ea,
                       unsigned long long* __restrict__ hist, int* __restrict__ rank, int E) {
    int e = blockIdx.x * 256 + threadIdx.x;
    if (e < E) {
        int d = ei[E + e];
        unsigned long long q = CNT_ONE |
            (unsigned long long)(unsigned)(ea[e] * 1048576.0f);
        unsigned long long old = atomicAdd(&hist[d], q);
        rank[e] = (int)(old >> 44);          // this edge's slot within dst's row
    }
}

// ---------------- pass 2: dinv + per-block exclusive scan of counts ----------------

__global__ void k_scan1(const unsigned long long* __restrict__ hist,
                        int* __restrict__ rp, int* __restrict__ bsums,
                        float* __restrict__ dinv, int n) {
    __shared__ int sh[256];
    int t = threadIdx.x;
    int i = blockIdx.x * 256 + t;
    int v = 0;
    if (i < n) {
        unsigned long long h = hist[i];
        v = (int)(h >> 44);
        float deg = 1.0f + (float)(h & SUM_MASK) * (1.0f / 1048576.0f);
        dinv[i] = rsqrtf(deg);               // deg >= 1 always (self loop)
    }
    sh[t] = v;
    __syncthreads();
    for (int off = 1; off < 256; off <<= 1) {
        int add = (t >= off) ? sh[t - off] : 0;
        __syncthreads();
        sh[t] += add;
        __syncthreads();
    }
    if (i < n) rp[i] = sh[t] - v;            // exclusive within block
    if (t == 255) bsums[blockIdx.x] = sh[255];
}

__global__ void k_scan2(int* __restrict__ bsums, int nb) {   // one block, 1024 threads
    __shared__ int sh[1024];
    int t = threadIdx.x;
    int v = (t < nb) ? bsums[t] : 0;
    sh[t] = v;
    __syncthreads();
    for (int off = 1; off < 1024; off <<= 1) {
        int add = (t >= off) ? sh[t - off] : 0;
        __syncthreads();
        sh[t] += add;
        __syncthreads();
    }
    if (t < nb) bsums[t] = sh[t] - v;        // exclusive
}

// ---------------- pass 3: CSR fill, atomic-free (slot = rp + bsum + rank) ----------------

__global__ void k_fill(const int* __restrict__ ei, const float* __restrict__ ea,
                       const float* __restrict__ dinv, const int* __restrict__ rp,
                       const int* __restrict__ bsums, const int* __restrict__ rank,
                       long long* __restrict__ csr, int E) {
    int e = blockIdx.x * 256 + threadIdx.x;
    if (e < E) {
        int s = ei[e];
        int d = ei[E + e];
        int slot = rp[d] + bsums[d >> 8] + rank[e];
        float nm = dinv[s] * ea[e] * dinv[d];
        long long packed = ((long long)__float_as_int(nm) << 32) | (unsigned int)s;
        __builtin_nontemporal_store(packed, csr + slot);   // random scatter: bypass cache
    }
}

// ---------------- main fused kernel ----------------
// block = 512 threads (8 waves), handles 16 nodes (2 nodes per wave).
// R4 theory: k_main is latency-bound (VALUBusy 11%, HBM 46%, Occ 64%), and the
// compiler serialized the per-thread gathers (VGPR=40 despite a 128 cap). So get
// concurrency from WAVES instead: LDS 24.8KB stays per-16-nodes, 8 waves/block
// -> 4 blocks/CU = 32 waves/CU = 100% occupancy (was 24 waves = 75% cap).
// __launch_bounds__(512,8) pins the 64-VGPR cap needed for 8 waves/EU (usage
// was 40, so no spill expected).
// Phase 2: threads 0..191 = (node_local, t); 32-wide W matmul (W uniform loads).
// Phase 3: coalesced non-temporal float4 stores.

__launch_bounds__(512, 8)
__global__ void k_main(const float* __restrict__ x, const float* __restrict__ W,
                       const float* __restrict__ b, const float* __restrict__ dinv,
                       const int* __restrict__ rp, const int* __restrict__ bsums,
                       const unsigned long long* __restrict__ hist,
                       const int2* __restrict__ csr, float* __restrict__ out, int n) {
    __shared__ float sAgg[16 * SROW];
    const int tid  = threadIdx.x;
    const int wave = tid >> 6;           // 0..7
    const int lane = tid & 63;
    const int base = blockIdx.x * 16;

    // ---- Phase 1: aggregation (2 nodes per wave) ----
    for (int q = 0; q < 2; ++q) {
        int nl = wave * 2 + q;
        int nd = base + nl;
        if (nd < n) {
            float sn = dinv[nd];
            sn = sn * sn;                       // self-loop norm
            const float2* xr = (const float2*)(x + (size_t)nd * FPN);
            float2 a0 = xr[lane], a1 = xr[lane + 64], a2 = xr[lane + 128];
            a0.x *= sn; a0.y *= sn; a1.x *= sn; a1.y *= sn; a2.x *= sn; a2.y *= sn;
            int st = rp[nd] + bsums[nd >> 8];
            int c  = (int)(hist[nd] >> 44);
            int j  = 0;
            for (; j + 4 <= c; j += 4) {
                int2 p0 = csr[st + j + 0];
                int2 p1 = csr[st + j + 1];
                int2 p2 = csr[st + j + 2];
                int2 p3 = csr[st + j + 3];
                const float2* s0 = (const float2*)(x + (size_t)p0.x * FPN);
                const float2* s1 = (const float2*)(x + (size_t)p1.x * FPN);
                const float2* s2 = (const float2*)(x + (size_t)p2.x * FPN);
                const float2* s3 = (const float2*)(x + (size_t)p3.x * FPN);
                // 12 independent gathers issued before any use
                float2 v00 = s0[lane], v01 = s0[lane + 64], v02 = s0[lane + 128];
                float2 v10 = s1[lane], v11 = s1[lane + 64], v12 = s1[lane + 128];
                float2 v20 = s2[lane], v21 = s2[lane + 64], v22 = s2[lane + 128];
                float2 v30 = s3[lane], v31 = s3[lane + 64], v32 = s3[lane + 128];
                float n0 = __int_as_float(p0.y), n1 = __int_as_float(p1.y);
                float n2 = __int_as_float(p2.y), n3 = __int_as_float(p3.y);
                a0.x = fmaf(n0, v00.x, a0.x); a0.y = fmaf(n0, v00.y, a0.y);
                a1.x = fmaf(n0, v01.x, a1.x); a1.y = fmaf(n0, v01.y, a1.y);
                a2.x = fmaf(n0, v02.x, a2.x); a2.y = fmaf(n0, v02.y, a2.y);
                a0.x = fmaf(n1, v10.x, a0.x); a0.y = fmaf(n1, v10.y, a0.y);
                a1.x = fmaf(n1, v11.x, a1.x); a1.y = fmaf(n1, v11.y, a1.y);
                a2.x = fmaf(n1, v12.x, a2.x); a2.y = fmaf(n1, v12.y, a2.y);
                a0.x = fmaf(n2, v20.x, a0.x); a0.y = fmaf(n2, v20.y, a0.y);
                a1.x = fmaf(n2, v21.x, a1.x); a1.y = fmaf(n2, v21.y, a1.y);
                a2.x = fmaf(n2, v22.x, a2.x); a2.y = fmaf(n2, v22.y, a2.y);
                a0.x = fmaf(n3, v30.x, a0.x); a0.y = fmaf(n3, v30.y, a0.y);
                a1.x = fmaf(n3, v31.x, a1.x); a1.y = fmaf(n3, v31.y, a1.y);
                a2.x = fmaf(n3, v32.x, a2.x); a2.y = fmaf(n3, v32.y, a2.y);
            }
            for (; j < c; ++j) {
                int2 p = csr[st + j];
                int   s  = p.x;
                float nm = __int_as_float(p.y);
                const float2* xs = (const float2*)(x + (size_t)s * FPN);
                float2 v0 = xs[lane], v1 = xs[lane + 64], v2 = xs[lane + 128];
                a0.x = fmaf(nm, v0.x, a0.x); a0.y = fmaf(nm, v0.y, a0.y);
                a1.x = fmaf(nm, v1.x, a1.x); a1.y = fmaf(nm, v1.y, a1.y);
                a2.x = fmaf(nm, v2.x, a2.x); a2.y = fmaf(nm, v2.y, a2.y);
            }
            float* ag = sAgg + nl * SROW;
            ((float2*)ag)[lane]       = a0;
            ((float2*)ag)[lane + 64]  = a1;
            ((float2*)ag)[lane + 128] = a2;
        }
    }
    __syncthreads();

    // ---- Phase 2: per-(node,t) W transform ----
    int nl = tid / 12;
    int t  = tid - nl * 12;
    bool act = (tid < 192) && (base + nl < n);
    float acc[COUT];
    if (act) {
        #pragma unroll
        for (int d = 0; d < COUT; ++d) acc[d] = b[d];
        const float* ag = sAgg + nl * SROW + t;
        #pragma unroll
        for (int c = 0; c < CIN; ++c) {
            float xv = ag[c * TT];
            #pragma unroll
            for (int d = 0; d < COUT; ++d) acc[d] = fmaf(xv, W[c * COUT + d], acc[d]);
        }
    }
    __syncthreads();
    if (act) {
        float* og = sAgg + nl * SROW;          // reuse LDS as output staging
        #pragma unroll
        for (int d = 0; d < COUT; ++d) og[d * TT + t] = acc[d];
    }
    __syncthreads();

    // ---- Phase 3: coalesced non-temporal store ----
    for (int m = tid; m < 16 * (FPN / 4); m += 512) {   // 16 * 96 float4
        int nl2 = m / 96;
        int off = m - nl2 * 96;
        int nd  = base + nl2;
        if (nd < n) {
            f4 v = *((const f4*)(sAgg + nl2 * SROW) + off);
            __builtin_nontemporal_store(v, (f4*)(out + (size_t)nd * FPN) + off);
        }
    }
}

// ---------------- launch ----------------

extern "C" void kernel_launch(void* const* d_in, const int* in_sizes, int n_in,
                              void* d_out, int out_size, void* d_ws, size_t ws_size,
                              hipStream_t stream) {
    const float* x  = (const float*)d_in[0];
    const int*   ei = (const int*)d_in[1];
    const float* ea = (const float*)d_in[2];
    const float* W  = (const float*)d_in[3];
    const float* b  = (const float*)d_in[4];
    float* out = (float*)d_out;

    const int E = in_sizes[2];            // 1,600,000
    const int N = in_sizes[0] / FPN;      // 100,000

    // workspace layout (8B-aligned first)
    char* w = (char*)d_ws;
    long long*          csr  = (long long*)w;           w += (size_t)E * sizeof(long long);
    unsigned long long* hist = (unsigned long long*)w;  w += (size_t)N * sizeof(unsigned long long);
    int*   rank  = (int*)w;                             w += (size_t)E * sizeof(int);
    float* dinv  = (float*)w;                           w += (size_t)N * sizeof(float);
    int*   rowp  = (int*)w;                             w += (size_t)N * sizeof(int);
    int*   bsums = (int*)w;

    const int NB = (N + 255) / 256;       // 391 blocks (<=1024 for scan2)
    const int EB = (E + 255) / 256;

    (void)hipMemsetAsync(hist, 0, (size_t)N * sizeof(unsigned long long), stream);

    k_hist<<<EB, 256, 0, stream>>>(ei, ea, hist, rank, E);
    k_scan1<<<NB, 256, 0, stream>>>(hist, rowp, bsums, dinv, N);
    k_scan2<<<1, 1024, 0, stream>>>(bsums, NB);
    k_fill<<<EB, 256, 0, stream>>>(ei, ea, dinv, rowp, bsums, rank, csr, E);

    const int MB = (N + 15) / 16;         // 6250 blocks
    k_main<<<MB, 512, 0, stream>>>(x, W, b, dinv, rowp, bsums, hist,
                                   (const int2*)csr, out, N);
}

// Round 2
// 590.619 us; speedup vs baseline: 1.1988x; 1.1964x over previous
//
#include <hip/hip_runtime.h>
#include <hip/hip_fp16.h>

// SpatialGraphConv: N=100000 nodes, CIN=COUT=32, T=12, E=1600000 edges.
// out[n,d,t] = b[d] + sum_c W[c,d] * agg[n,c,t],
// agg[n,:,:] = dinv[n]^2 * x[n,:,:] + sum_{e: dst=n} dinv[src]*w_e*dinv[n] * x[src,:,:]
// deg[n] = 1.0 (self loop) + sum_{e: dst=n} edge_attr[e];  dinv = rsqrt(deg)
//
// R2: k_main is at a random-chunk HBM ceiling (R1: occupancy 64->86% gave +0%,
// FETCH 1.26GB vs 2.46GB of gather requests -> ~50% LLC hit on a 153.6MB
// footprint). Fix the BYTES, not the latency: gather from an fp16 shadow of x
// (768B/row, 76.8MB footprint -> fits LLC slice). Self term + accumulation stay
// fp32. Conversion fused into k_hist (hidden under its atomic latency).

constexpr int CIN  = 32;
constexpr int TT   = 12;
constexpr int COUT = 32;
constexpr int FPN  = CIN * TT;   // 384 floats per node row
constexpr int SROW = 388;        // padded LDS row

typedef float f4 __attribute__((ext_vector_type(4)));   // native vec for nontemporal

// Packed histogram: bits [44,64) = edge count, bits [0,44) = sum(ea) in 2^-20 fixed point.
constexpr unsigned long long CNT_ONE = 1ULL << 44;
constexpr unsigned long long SUM_MASK = CNT_ONE - 1;

// ---------------- pass 1: packed histogram + per-edge rank (+ fp16 x shadow) ----------------

__global__ void k_hist(const int* __restrict__ ei, const float* __restrict__ ea,
                       unsigned long long* __restrict__ hist, int* __restrict__ rank,
                       const float2* __restrict__ xf2, __half2* __restrict__ xh2,
                       long long nf2, int E) {
    int e = blockIdx.x * 256 + threadIdx.x;
    if (e < E) {
        int d = ei[E + e];
        unsigned long long q = CNT_ONE |
            (unsigned long long)(unsigned)(ea[e] * 1048576.0f);
        unsigned long long old = atomicAdd(&hist[d], q);
        rank[e] = (int)(old >> 44);          // this edge's slot within dst's row
    }
    // fused fp16 shadow build: streams 230MB under the atomic-bound edge pass
    if (xh2) {
        long long stride = (long long)gridDim.x * 256;
        for (long long i = blockIdx.x * 256LL + threadIdx.x; i < nf2; i += stride) {
            xh2[i] = __float22half2_rn(xf2[i]);
        }
    }
}

// ---------------- pass 2: dinv + per-block exclusive scan of counts ----------------

__global__ void k_scan1(const unsigned long long* __restrict__ hist,
                        int* __restrict__ rp, int* __restrict__ bsums,
                        float* __restrict__ dinv, int n) {
    __shared__ int sh[256];
    int t = threadIdx.x;
    int i = blockIdx.x * 256 + t;
    int v = 0;
    if (i < n) {
        unsigned long long h = hist[i];
        v = (int)(h >> 44);
        float deg = 1.0f + (float)(h & SUM_MASK) * (1.0f / 1048576.0f);
        dinv[i] = rsqrtf(deg);               // deg >= 1 always (self loop)
    }
    sh[t] = v;
    __syncthreads();
    for (int off = 1; off < 256; off <<= 1) {
        int add = (t >= off) ? sh[t - off] : 0;
        __syncthreads();
        sh[t] += add;
        __syncthreads();
    }
    if (i < n) rp[i] = sh[t] - v;            // exclusive within block
    if (t == 255) bsums[blockIdx.x] = sh[255];
}

__global__ void k_scan2(int* __restrict__ bsums, int nb) {   // one block, 1024 threads
    __shared__ int sh[1024];
    int t = threadIdx.x;
    int v = (t < nb) ? bsums[t] : 0;
    sh[t] = v;
    __syncthreads();
    for (int off = 1; off < 1024; off <<= 1) {
        int add = (t >= off) ? sh[t - off] : 0;
        __syncthreads();
        sh[t] += add;
        __syncthreads();
    }
    if (t < nb) bsums[t] = sh[t] - v;        // exclusive
}

// ---------------- pass 3: CSR fill, atomic-free (slot = rp + bsum + rank) ----------------

__global__ void k_fill(const int* __restrict__ ei, const float* __restrict__ ea,
                       const float* __restrict__ dinv, const int* __restrict__ rp,
                       const int* __restrict__ bsums, const int* __restrict__ rank,
                       long long* __restrict__ csr, int E) {
    int e = blockIdx.x * 256 + threadIdx.x;
    if (e < E) {
        int s = ei[e];
        int d = ei[E + e];
        int slot = rp[d] + bsums[d >> 8] + rank[e];
        float nm = dinv[s] * ea[e] * dinv[d];
        long long packed = ((long long)__float_as_int(nm) << 32) | (unsigned int)s;
        __builtin_nontemporal_store(packed, csr + slot);   // random scatter: bypass cache
    }
}

// ---------------- main fused kernel ----------------
// block = 512 threads (8 waves), 16 nodes (2 per wave).
// USE_H: gather neighbor rows from the fp16 shadow (768B/row). Self term fp32.

template <bool USE_H>
__launch_bounds__(512, 8)
__global__ void k_main(const float* __restrict__ x, const __half* __restrict__ xh,
                       const float* __restrict__ W,
                       const float* __restrict__ b, const float* __restrict__ dinv,
                       const int* __restrict__ rp, const int* __restrict__ bsums,
                       const unsigned long long* __restrict__ hist,
                       const int2* __restrict__ csr, float* __restrict__ out, int n) {
    __shared__ float sAgg[16 * SROW];
    const int tid  = threadIdx.x;
    const int wave = tid >> 6;           // 0..7
    const int lane = tid & 63;
    const int base = blockIdx.x * 16;

    // ---- Phase 1: aggregation (2 nodes per wave) ----
    for (int q = 0; q < 2; ++q) {
        int nl = wave * 2 + q;
        int nd = base + nl;
        if (nd < n) {
            float sn = dinv[nd];
            sn = sn * sn;                       // self-loop norm
            const float2* xr = (const float2*)(x + (size_t)nd * FPN);
            float2 a0 = xr[lane], a1 = xr[lane + 64], a2 = xr[lane + 128];
            a0.x *= sn; a0.y *= sn; a1.x *= sn; a1.y *= sn; a2.x *= sn; a2.y *= sn;
            int st = rp[nd] + bsums[nd >> 8];
            int c  = (int)(hist[nd] >> 44);
            int j  = 0;
            for (; j + 4 <= c; j += 4) {
                int2 p0 = csr[st + j + 0];
                int2 p1 = csr[st + j + 1];
                int2 p2 = csr[st + j + 2];
                int2 p3 = csr[st + j + 3];
                float2 v00, v01, v02, v10, v11, v12;
                float2 v20, v21, v22, v30, v31, v32;
                if constexpr (USE_H) {
                    const __half2* s0 = (const __half2*)(xh + (size_t)p0.x * FPN);
                    const __half2* s1 = (const __half2*)(xh + (size_t)p1.x * FPN);
                    const __half2* s2 = (const __half2*)(xh + (size_t)p2.x * FPN);
                    const __half2* s3 = (const __half2*)(xh + (size_t)p3.x * FPN);
                    // 12 independent 4B gathers issued before any use
                    __half2 h00 = s0[lane], h01 = s0[lane + 64], h02 = s0[lane + 128];
                    __half2 h10 = s1[lane], h11 = s1[lane + 64], h12 = s1[lane + 128];
                    __half2 h20 = s2[lane], h21 = s2[lane + 64], h22 = s2[lane + 128];
                    __half2 h30 = s3[lane], h31 = s3[lane + 64], h32 = s3[lane + 128];
                    v00 = __half22float2(h00); v01 = __half22float2(h01); v02 = __half22float2(h02);
                    v10 = __half22float2(h10); v11 = __half22float2(h11); v12 = __half22float2(h12);
                    v20 = __half22float2(h20); v21 = __half22float2(h21); v22 = __half22float2(h22);
                    v30 = __half22float2(h30); v31 = __half22float2(h31); v32 = __half22float2(h32);
                } else {
                    const float2* s0 = (const float2*)(x + (size_t)p0.x * FPN);
                    const float2* s1 = (const float2*)(x + (size_t)p1.x * FPN);
                    const float2* s2 = (const float2*)(x + (size_t)p2.x * FPN);
                    const float2* s3 = (const float2*)(x + (size_t)p3.x * FPN);
                    v00 = s0[lane]; v01 = s0[lane + 64]; v02 = s0[lane + 128];
                    v10 = s1[lane]; v11 = s1[lane + 64]; v12 = s1[lane + 128];
                    v20 = s2[lane]; v21 = s2[lane + 64]; v22 = s2[lane + 128];
                    v30 = s3[lane]; v31 = s3[lane + 64]; v32 = s3[lane + 128];
                }
                float n0 = __int_as_float(p0.y), n1 = __int_as_float(p1.y);
                float n2 = __int_as_float(p2.y), n3 = __int_as_float(p3.y);
                a0.x = fmaf(n0, v00.x, a0.x); a0.y = fmaf(n0, v00.y, a0.y);
                a1.x = fmaf(n0, v01.x, a1.x); a1.y = fmaf(n0, v01.y, a1.y);
                a2.x = fmaf(n0, v02.x, a2.x); a2.y = fmaf(n0, v02.y, a2.y);
                a0.x = fmaf(n1, v10.x, a0.x); a0.y = fmaf(n1, v10.y, a0.y);
                a1.x = fmaf(n1, v11.x, a1.x); a1.y = fmaf(n1, v11.y, a1.y);
                a2.x = fmaf(n1, v12.x, a2.x); a2.y = fmaf(n1, v12.y, a2.y);
                a0.x = fmaf(n2, v20.x, a0.x); a0.y = fmaf(n2, v20.y, a0.y);
                a1.x = fmaf(n2, v21.x, a1.x); a1.y = fmaf(n2, v21.y, a1.y);
                a2.x = fmaf(n2, v22.x, a2.x); a2.y = fmaf(n2, v22.y, a2.y);
                a0.x = fmaf(n3, v30.x, a0.x); a0.y = fmaf(n3, v30.y, a0.y);
                a1.x = fmaf(n3, v31.x, a1.x); a1.y = fmaf(n3, v31.y, a1.y);
                a2.x = fmaf(n3, v32.x, a2.x); a2.y = fmaf(n3, v32.y, a2.y);
            }
            for (; j < c; ++j) {
                int2 p = csr[st + j];
                int   s  = p.x;
                float nm = __int_as_float(p.y);
                float2 v0, v1, v2;
                if constexpr (USE_H) {
                    const __half2* xs = (const __half2*)(xh + (size_t)s * FPN);
                    v0 = __half22float2(xs[lane]);
                    v1 = __half22float2(xs[lane + 64]);
                    v2 = __half22float2(xs[lane + 128]);
                } else {
                    const float2* xs = (const float2*)(x + (size_t)s * FPN);
                    v0 = xs[lane]; v1 = xs[lane + 64]; v2 = xs[lane + 128];
                }
                a0.x = fmaf(nm, v0.x, a0.x); a0.y = fmaf(nm, v0.y, a0.y);
                a1.x = fmaf(nm, v1.x, a1.x); a1.y = fmaf(nm, v1.y, a1.y);
                a2.x = fmaf(nm, v2.x, a2.x); a2.y = fmaf(nm, v2.y, a2.y);
            }
            float* ag = sAgg + nl * SROW;
            ((float2*)ag)[lane]       = a0;
            ((float2*)ag)[lane + 64]  = a1;
            ((float2*)ag)[lane + 128] = a2;
        }
    }
    __syncthreads();

    // ---- Phase 2: per-(node,t) W transform ----
    int nl = tid / 12;
    int t  = tid - nl * 12;
    bool act = (tid < 192) && (base + nl < n);
    float acc[COUT];
    if (act) {
        #pragma unroll
        for (int d = 0; d < COUT; ++d) acc[d] = b[d];
        const float* ag = sAgg + nl * SROW + t;
        #pragma unroll
        for (int c = 0; c < CIN; ++c) {
            float xv = ag[c * TT];
            #pragma unroll
            for (int d = 0; d < COUT; ++d) acc[d] = fmaf(xv, W[c * COUT + d], acc[d]);
        }
    }
    __syncthreads();
    if (act) {
        float* og = sAgg + nl * SROW;          // reuse LDS as output staging
        #pragma unroll
        for (int d = 0; d < COUT; ++d) og[d * TT + t] = acc[d];
    }
    __syncthreads();

    // ---- Phase 3: coalesced non-temporal store ----
    for (int m = tid; m < 16 * (FPN / 4); m += 512) {   // 16 * 96 float4
        int nl2 = m / 96;
        int off = m - nl2 * 96;
        int nd  = base + nl2;
        if (nd < n) {
            f4 v = *((const f4*)(sAgg + nl2 * SROW) + off);
            __builtin_nontemporal_store(v, (f4*)(out + (size_t)nd * FPN) + off);
        }
    }
}

// ---------------- launch ----------------

extern "C" void kernel_launch(void* const* d_in, const int* in_sizes, int n_in,
                              void* d_out, int out_size, void* d_ws, size_t ws_size,
                              hipStream_t stream) {
    const float* x  = (const float*)d_in[0];
    const int*   ei = (const int*)d_in[1];
    const float* ea = (const float*)d_in[2];
    const float* W  = (const float*)d_in[3];
    const float* b  = (const float*)d_in[4];
    float* out = (float*)d_out;

    const int E = in_sizes[2];            // 1,600,000
    const int N = in_sizes[0] / FPN;      // 100,000

    // workspace layout (8B-aligned first)
    char* w = (char*)d_ws;
    long long*          csr  = (long long*)w;           w += (size_t)E * sizeof(long long);
    unsigned long long* hist = (unsigned long long*)w;  w += (size_t)N * sizeof(unsigned long long);
    __half* xh = (__half*)w;   // fp16 shadow of x, 76.8MB (optional)
    size_t xh_bytes = (size_t)N * FPN * sizeof(__half);
    size_t fixed = (size_t)E * 8 + (size_t)N * 8 + (size_t)E * 4 + (size_t)N * 4
                 + (size_t)N * 4 + 8192;
    bool use_h = (ws_size >= fixed + xh_bytes);
    if (use_h) w += xh_bytes; else xh = nullptr;
    int*   rank  = (int*)w;                             w += (size_t)E * sizeof(int);
    float* dinv  = (float*)w;                           w += (size_t)N * sizeof(float);
    int*   rowp  = (int*)w;                             w += (size_t)N * sizeof(int);
    int*   bsums = (int*)w;

    const int NB = (N + 255) / 256;       // 391 blocks (<=1024 for scan2)
    const int EB = (E + 255) / 256;

    (void)hipMemsetAsync(hist, 0, (size_t)N * sizeof(unsigned long long), stream);

    long long nf2 = (long long)N * (FPN / 2);
    k_hist<<<EB, 256, 0, stream>>>(ei, ea, hist, rank,
                                   (const float2*)x, (__half2*)xh, nf2, E);
    k_scan1<<<NB, 256, 0, stream>>>(hist, rowp, bsums, dinv, N);
    k_scan2<<<1, 1024, 0, stream>>>(bsums, NB);
    k_fill<<<EB, 256, 0, stream>>>(ei, ea, dinv, rowp, bsums, rank, csr, E);

    const int MB = (N + 15) / 16;         // 6250 blocks
    if (use_h) {
        k_main<true><<<MB, 512, 0, stream>>>(x, xh, W, b, dinv, rowp, bsums, hist,
                                             (const int2*)csr, out, N);
    } else {
        k_main<false><<<MB, 512, 0, stream>>>(x, xh, W, b, dinv, rowp, bsums, hist,
                                              (const int2*)csr, out, N);
    }
}